// Round 8
// baseline (2815.678 us; speedup 1.0000x reference)
//
#include <hip/hip_runtime.h>
#include <hip/hip_bf16.h>
#include <math.h>

#define D_MODEL 512
#define NHEAD   8
#define DHEAD   64
#define SEQ     64
#define BATCH   256
#define NLAYER  8
#define VOCAB   66
#define FFDIM   2048
#define NTOK    (BATCH * SEQ)   // 16384 rows

typedef __attribute__((ext_vector_type(8))) short short8;    // 8 bf16 = 4 VGPRs
typedef __attribute__((ext_vector_type(4))) float f32x4;
typedef __attribute__((ext_vector_type(16))) float f32x16;

__device__ inline void async_copy16(const void* g, void* l) {
    __builtin_amdgcn_global_load_lds(
        (const __attribute__((address_space(1))) void*)g,
        (__attribute__((address_space(3))) void*)l,
        16, 0, 0);
}

// ---------------- weight fp32 [K,M] -> bf16 [M,K] transpose ----------------
__global__ __launch_bounds__(256) void transpose_conv(
        const float* __restrict__ W, __hip_bfloat16* __restrict__ Wt,
        int K, int M, size_t inLS, size_t outLS, int rowOff) {
    __shared__ float tile[32][33];
    int m0 = blockIdx.x * 32, k0 = blockIdx.y * 32;
    const float* Wl = W + blockIdx.z * inLS;
    __hip_bfloat16* Wtl = Wt + blockIdx.z * outLS;
    int t = threadIdx.x;
    #pragma unroll
    for (int p = 0; p < 4; p++) {
        int idx = t + p * 256;
        int kr = idx >> 5, mc = idx & 31;
        tile[kr][mc] = Wl[(size_t)(k0 + kr) * M + m0 + mc];
    }
    __syncthreads();
    #pragma unroll
    for (int p = 0; p < 4; p++) {
        int idx = t + p * 256;
        int mr = idx >> 5, kc = idx & 31;
        Wtl[(size_t)(rowOff + m0 + mr) * K + k0 + kc] = __float2bfloat16(tile[kc][mr]);
    }
}

// ---------------- Wu fp32 [512,66] -> bf16 [128,512] transposed, zero-padded ----
__global__ __launch_bounds__(256) void conv_wu(
        const float* __restrict__ Wu, __hip_bfloat16* __restrict__ WuT) {
    int idx = blockIdx.x * 256 + threadIdx.x;   // over 128*512
    int m = idx >> 9, k = idx & 511;
    WuT[idx] = __float2bfloat16(m < VOCAB ? Wu[(size_t)k * VOCAB + m] : 0.f);
}

// ---------------- embedding (fp32 residual) ----------------
__global__ void embed_kernel(const int* __restrict__ ids, const float* __restrict__ tok,
                             const float* __restrict__ pos, float* __restrict__ x) {
    int idx = blockIdx.x * 256 + threadIdx.x;
    int n = idx >> 9;
    int d = idx & 511;
    int s = n & (SEQ - 1);
    x[idx] = tok[ids[n] * D_MODEL + d] + pos[s * D_MODEL + d];
}

// ---------------- layernorm: wave per row, no barriers ----------------
__global__ __launch_bounds__(256) void ln_kernel(
        const float* __restrict__ x, const float* __restrict__ g,
        const float* __restrict__ b, __hip_bfloat16* __restrict__ y) {
    int row = blockIdx.x * 4 + (threadIdx.x >> 6);
    int lane = threadIdx.x & 63;
    const float* xr = x + (size_t)row * D_MODEL + lane * 8;
    f32x4 v0 = *(const f32x4*)xr;
    f32x4 v1 = *(const f32x4*)(xr + 4);
    float s = 0.f, ss = 0.f;
    #pragma unroll
    for (int e = 0; e < 4; e++) { s += v0[e] + v1[e]; ss += v0[e] * v0[e] + v1[e] * v1[e]; }
    #pragma unroll
    for (int o = 1; o < 64; o <<= 1) {
        s  += __shfl_xor(s, o);
        ss += __shfl_xor(ss, o);
    }
    float mean = s / (float)D_MODEL;
    float var = (ss - (float)D_MODEL * mean * mean) / (float)(D_MODEL - 1);
    float denom = sqrtf(fmaxf(var, 0.f)) + 1e-10f;
    f32x4 g0 = *(const f32x4*)(g + lane * 8);
    f32x4 g1 = *(const f32x4*)(g + lane * 8 + 4);
    f32x4 b0 = *(const f32x4*)(b + lane * 8);
    f32x4 b1 = *(const f32x4*)(b + lane * 8 + 4);
    short8 outv;
    #pragma unroll
    for (int e = 0; e < 4; e++) {
        outv[e]     = ((__hip_bfloat16_raw)__float2bfloat16((v0[e] - mean) / denom * g0[e] + b0[e])).x;
        outv[e + 4] = ((__hip_bfloat16_raw)__float2bfloat16((v1[e] - mean) / denom * g1[e] + b1[e])).x;
    }
    *(short8*)((short*)y + (size_t)row * D_MODEL + lane * 8) = outv;
}

// ---------------- GEMM v3: A dbuf-LDS (1 barrier/iter), B direct-from-L2 ----------------
// A [N,K] bf16 row-major staged through 2x16KB LDS buffers (XOR-swizzled);
// Bt [M,K] bf16 (weights, L2-resident) loaded straight into VGPR fragments.
// Copies for iter k+1 are issued right AFTER the barrier that publishes iter k,
// so the next barrier's vmcnt(0) drain finds them mostly landed.
// 128x128 tile, BK=64, 4 waves 2x2 of 64x64 (2x2 of 32x32 MFMA).
// OUTMODE 0: bf16 store (+optional GELU). 1: fp32 store + addsrc residual.
template <int ACT, int OUTMODE>
__global__ __launch_bounds__(256) void mfma_gemm2(
        const __hip_bfloat16* __restrict__ A, const __hip_bfloat16* __restrict__ Bt,
        const float* __restrict__ bias, const float* addsrc,
        void* Cout, int K, int M) {
    __shared__ __align__(16) short As[2][128 * 64];   // 2 x 16 KB
    int tid = threadIdx.x;
    int lane = tid & 63, wave = tid >> 6;
    int row0 = blockIdx.y * 128, col0 = blockIdx.x * 128;
    int wr = (wave >> 1) * 64, wc = (wave & 1) * 64;
    int l31 = lane & 31, h32 = lane >> 5;
    int l7 = l31 & 7;

    f32x16 acc[2][2] = {};

    // staging source offsets (swizzled): chunk u holds global (row=u>>3, kg=(u&7)^(row&7))
    int srow[4], skg[4];
    #pragma unroll
    for (int s = 0; s < 4; s++) {
        int u = s * 256 + tid;
        srow[s] = u >> 3;
        skg[s] = (u & 7) ^ (srow[s] & 7);
    }

    const short* Ab = (const short*)A + (size_t)row0 * K;
    const short* Bg0 = (const short*)Bt + (size_t)(col0 + wc + l31) * K;
    const short* Bg1 = (const short*)Bt + (size_t)(col0 + wc + 32 + l31) * K;

    int niter = K >> 6;
    // prologue: stage tile 0 into buf 0
    #pragma unroll
    for (int s = 0; s < 4; s++)
        async_copy16(Ab + (size_t)srow[s] * K + skg[s] * 8, &As[0][(s * 256 + tid) * 8]);

    for (int it = 0; it < niter; it++) {
        __syncthreads();   // publishes buf[it&1] (drains its copies + last iter's reads)
        if (it + 1 < niter) {
            int k1 = (it + 1) << 6;
            #pragma unroll
            for (int s = 0; s < 4; s++)
                async_copy16(Ab + (size_t)srow[s] * K + k1 + skg[s] * 8,
                             &As[(it + 1) & 1][(s * 256 + tid) * 8]);
        }
        const short* Ac = &As[it & 1][0];
        int k0 = it << 6;
        #pragma unroll
        for (int kk = 0; kk < 4; kk++) {
            int kg = kk * 2 + h32;
            int c = kg ^ l7;
            short8 af0 = *(const short8*)(Ac + ((wr + l31) * 8 + c) * 8);
            short8 af1 = *(const short8*)(Ac + ((wr + 32 + l31) * 8 + c) * 8);
            short8 bf0 = *(const short8*)(Bg0 + k0 + kg * 8);
            short8 bf1 = *(const short8*)(Bg1 + k0 + kg * 8);
            acc[0][0] = __builtin_amdgcn_mfma_f32_32x32x16_bf16(af0, bf0, acc[0][0], 0, 0, 0);
            acc[0][1] = __builtin_amdgcn_mfma_f32_32x32x16_bf16(af0, bf1, acc[0][1], 0, 0, 0);
            acc[1][0] = __builtin_amdgcn_mfma_f32_32x32x16_bf16(af1, bf0, acc[1][0], 0, 0, 0);
            acc[1][1] = __builtin_amdgcn_mfma_f32_32x32x16_bf16(af1, bf1, acc[1][1], 0, 0, 0);
        }
    }

    // C/D layout: col = lane&31, row = (reg&3) + 8*(reg>>2) + 4*(lane>>5)
    #pragma unroll
    for (int j = 0; j < 2; j++) {
        int col = col0 + wc + j * 32 + l31;
        float bv = bias ? bias[col] : 0.f;
        #pragma unroll
        for (int i = 0; i < 2; i++) {
            int rbase = row0 + wr + i * 32 + 4 * h32;
            #pragma unroll
            for (int r = 0; r < 16; r++) {
                int row = rbase + (r & 3) + 8 * (r >> 2);
                float v = acc[i][j][r] + bv;
                if (OUTMODE == 1) v += addsrc[(size_t)row * M + col];
                if (ACT == 1) v = 0.5f * v * (1.f + erff(v * 0.70710678118654752f));
                if (OUTMODE == 0)
                    ((__hip_bfloat16*)Cout)[(size_t)row * M + col] = __float2bfloat16(v);
                else
                    ((float*)Cout)[(size_t)row * M + col] = v;
            }
        }
    }
}

// ---------------- legacy GEMM (32x32x16, BK=64) for logits (OUTMODE 2) ----------------
template <int ACT, int OUTMODE>
__global__ __launch_bounds__(256) void mfma_gemm(
        const __hip_bfloat16* __restrict__ A, const __hip_bfloat16* __restrict__ Bt,
        const float* __restrict__ bias, const float* addsrc,
        void* Cout, int K, int M, int ldc, int mstore) {
    __shared__ __align__(16) short As[128 * 64];
    __shared__ __align__(16) short Bs[128 * 64];
    int tid = threadIdx.x;
    int lane = tid & 63, wave = tid >> 6;
    int row0 = blockIdx.y * 128, col0 = blockIdx.x * 128;
    int wr = (wave >> 1) * 64, wc = (wave & 1) * 64;
    int l31 = lane & 31, h32 = lane >> 5;
    int l7 = l31 & 7;

    f32x16 acc[2][2] = {};

    int srow[4], skg[4];
    #pragma unroll
    for (int s = 0; s < 4; s++) {
        int u = s * 256 + tid;
        srow[s] = u >> 3;
        skg[s] = (u & 7) ^ (srow[s] & 7);
    }

    for (int k0 = 0; k0 < K; k0 += 64) {
        #pragma unroll
        for (int s = 0; s < 4; s++) {
            int u = s * 256 + tid;
            async_copy16((const short*)A + (size_t)(row0 + srow[s]) * K + k0 + skg[s] * 8,
                         As + u * 8);
            async_copy16((const short*)Bt + (size_t)(col0 + srow[s]) * K + k0 + skg[s] * 8,
                         Bs + u * 8);
        }
        __syncthreads();
        short8 af[2][4], bf[2][4];
        #pragma unroll
        for (int i = 0; i < 2; i++)
            #pragma unroll
            for (int kk = 0; kk < 4; kk++) {
                int kg = kk * 2 + h32;
                int c = kg ^ l7;
                af[i][kk] = *(const short8*)(As + ((wr + i * 32 + l31) * 8 + c) * 8);
                bf[i][kk] = *(const short8*)(Bs + ((wc + i * 32 + l31) * 8 + c) * 8);
            }
        #pragma unroll
        for (int i = 0; i < 2; i++)
            #pragma unroll
            for (int j = 0; j < 2; j++)
                #pragma unroll
                for (int kk = 0; kk < 4; kk++)
                    acc[i][j] = __builtin_amdgcn_mfma_f32_32x32x16_bf16(
                        af[i][kk], bf[j][kk], acc[i][j], 0, 0, 0);
        __syncthreads();
    }

    #pragma unroll
    for (int j = 0; j < 2; j++) {
        int col = col0 + wc + j * 32 + l31;
        if (OUTMODE == 2 && col >= mstore) continue;
        float bv = bias ? bias[col] : 0.f;
        #pragma unroll
        for (int i = 0; i < 2; i++) {
            int rbase = row0 + wr + i * 32 + 4 * h32;
            #pragma unroll
            for (int r = 0; r < 16; r++) {
                int row = rbase + (r & 3) + 8 * (r >> 2);
                float v = acc[i][j][r] + bv;
                if (OUTMODE == 1) v += addsrc[(size_t)row * M + col];
                if (ACT == 1) v = 0.5f * v * (1.f + erff(v * 0.70710678118654752f));
                if (OUTMODE == 0)
                    ((__hip_bfloat16*)Cout)[(size_t)row * M + col] = __float2bfloat16(v);
                else
                    ((float*)Cout)[(size_t)row * ldc + col] = v;
            }
        }
    }
}

// ---------------- MFMA causal attention: one block per (b,h) ----------------
#define PSTRIDE 72
__global__ __launch_bounds__(256) void attn_mfma(
        const __hip_bfloat16* __restrict__ QKV, __hip_bfloat16* __restrict__ O) {
    __shared__ __align__(16) short Vt[64 * PSTRIDE];   // Vt[c][j] = V[j][c]
    __shared__ __align__(16) short P[64 * PSTRIDE];    // P[r][j]
    int bh = blockIdx.x;
    int b = bh >> 3, h = bh & 7;
    int t = threadIdx.x;
    int lane = t & 63, wave = t >> 6;
    int l15 = lane & 15, quad = lane >> 4;
    const float scale = 0.04419417382415922f;  // 1/sqrt(512)
    const short* base = (const short*)QKV + (size_t)(b * SEQ) * 1536 + h * DHEAD;

    // cooperative V transpose into LDS
    {
        int j0 = (t >> 3) * 2;
        int c0 = (t & 7) * 8;
        const short* vrow = base + 1024 + (size_t)j0 * 1536 + c0;
        short8 va = *(const short8*)vrow;
        short8 vb = *(const short8*)(vrow + 1536);
        #pragma unroll
        for (int s = 0; s < 8; s++) {
            unsigned int packed = ((unsigned int)(unsigned short)vb[s] << 16) |
                                  (unsigned int)(unsigned short)va[s];
            *(unsigned int*)&Vt[(c0 + s) * PSTRIDE + j0] = packed;
        }
    }

    // QK^T for this wave's 16 rows
    int r0 = wave * 16;
    short8 aq[2], bk[4][2];
    #pragma unroll
    for (int k = 0; k < 2; k++)
        aq[k] = *(const short8*)(base + (size_t)(r0 + l15) * 1536 + quad * 8 + 32 * k);
    #pragma unroll
    for (int j = 0; j < 4; j++)
        #pragma unroll
        for (int k = 0; k < 2; k++)
            bk[j][k] = *(const short8*)(base + 512 + (size_t)(j * 16 + l15) * 1536 + quad * 8 + 32 * k);

    f32x4 sc[4];
    #pragma unroll
    for (int j = 0; j < 4; j++) {
        f32x4 z = {};
        z = __builtin_amdgcn_mfma_f32_16x16x32_bf16(aq[0], bk[j][0], z, 0, 0, 0);
        sc[j] = __builtin_amdgcn_mfma_f32_16x16x32_bf16(aq[1], bk[j][1], z, 0, 0, 0);
    }

    // softmax per row
    float p[4][4];
    #pragma unroll
    for (int reg = 0; reg < 4; reg++) {
        int r = r0 + quad * 4 + reg;
        float m = -INFINITY;
        #pragma unroll
        for (int j = 0; j < 4; j++) {
            int c = j * 16 + l15;
            float s = (c <= r) ? sc[j][reg] * scale : -INFINITY;
            p[j][reg] = s;
            m = fmaxf(m, s);
        }
        #pragma unroll
        for (int o = 1; o < 16; o <<= 1) m = fmaxf(m, __shfl_xor(m, o));
        float sum = 0.f;
        #pragma unroll
        for (int j = 0; j < 4; j++) {
            float e = (p[j][reg] == -INFINITY) ? 0.f : expf(p[j][reg] - m);
            p[j][reg] = e;
            sum += e;
        }
        #pragma unroll
        for (int o = 1; o < 16; o <<= 1) sum += __shfl_xor(sum, o);
        float inv = 1.f / sum;
        #pragma unroll
        for (int j = 0; j < 4; j++) p[j][reg] *= inv;
    }

    // write P (bf16) to LDS
    #pragma unroll
    for (int j = 0; j < 4; j++)
        #pragma unroll
        for (int reg = 0; reg < 4; reg++) {
            int r = r0 + quad * 4 + reg;
            P[r * PSTRIDE + j * 16 + l15] =
                ((__hip_bfloat16_raw)__float2bfloat16(p[j][reg])).x;
        }

    __syncthreads();

    // PV
    short8 ap[2];
    #pragma unroll
    for (int k = 0; k < 2; k++)
        ap[k] = *(const short8*)(P + (r0 + l15) * PSTRIDE + quad * 8 + 32 * k);
    #pragma unroll
    for (int jt = 0; jt < 4; jt++) {
        short8 bv0 = *(const short8*)(Vt + (jt * 16 + l15) * PSTRIDE + quad * 8);
        short8 bv1 = *(const short8*)(Vt + (jt * 16 + l15) * PSTRIDE + quad * 8 + 32);
        f32x4 o = {};
        o = __builtin_amdgcn_mfma_f32_16x16x32_bf16(ap[0], bv0, o, 0, 0, 0);
        o = __builtin_amdgcn_mfma_f32_16x16x32_bf16(ap[1], bv1, o, 0, 0, 0);
        #pragma unroll
        for (int reg = 0; reg < 4; reg++) {
            int r = r0 + quad * 4 + reg;
            int c = jt * 16 + l15;
            O[(size_t)(b * SEQ + r) * D_MODEL + h * DHEAD + c] = __float2bfloat16(o[reg]);
        }
    }
}

// ---------------- loss: grid-stride waves, one atomic per wave ----------------
__global__ void zero_kernel(float* p) { if (threadIdx.x == 0) *p = 0.f; }

__global__ __launch_bounds__(256) void loss_kernel(
        const float* __restrict__ lg, const int* __restrict__ tgt,
        float* __restrict__ loss) {
    int wave = threadIdx.x >> 6;
    int l = threadIdx.x & 63;
    float local = 0.f;
    for (int row = blockIdx.x * 4 + wave; row < NTOK; row += gridDim.x * 4) {
        const float* lr = lg + (size_t)row * VOCAB;
        float a = lr[l];
        float bx = (l < VOCAB - 64) ? lr[64 + l] : -INFINITY;
        float m = fmaxf(a, bx);
        #pragma unroll
        for (int o = 32; o >= 1; o >>= 1) m = fmaxf(m, __shfl_xor(m, o));
        float s = expf(a - m) + ((l < VOCAB - 64) ? expf(bx - m) : 0.f);
        #pragma unroll
        for (int o = 32; o >= 1; o >>= 1) s += __shfl_xor(s, o);
        if (l == 0) local += lr[tgt[row]] - m - logf(s);
    }
    if (l == 0) atomicAdd(loss, -local / (float)NTOK);
}

extern "C" void kernel_launch(void* const* d_in, const int* in_sizes, int n_in,
                              void* d_out, int out_size, void* d_ws, size_t ws_size,
                              hipStream_t stream) {
    const int*   input_ids = (const int*)  d_in[0];
    const int*   targets   = (const int*)  d_in[1];
    const float* tok_emb   = (const float*)d_in[2];
    const float* pos_emb   = (const float*)d_in[3];
    const float* Wq        = (const float*)d_in[4];
    const float* Wk        = (const float*)d_in[5];
    const float* Wv        = (const float*)d_in[6];
    const float* Wo        = (const float*)d_in[7];
    const float* bo        = (const float*)d_in[8];
    const float* W1        = (const float*)d_in[9];
    const float* b1        = (const float*)d_in[10];
    const float* W2        = (const float*)d_in[11];
    const float* b2        = (const float*)d_in[12];
    const float* ln1_g     = (const float*)d_in[13];
    const float* ln1_b     = (const float*)d_in[14];
    const float* ln2_g     = (const float*)d_in[15];
    const float* ln2_b     = (const float*)d_in[16];
    const float* lnf_g     = (const float*)d_in[17];
    const float* lnf_b     = (const float*)d_in[18];
    const float* Wu        = (const float*)d_in[19];
    const float* bu        = (const float*)d_in[20];

    float* out  = (float*)d_out;
    float* loss = out + (size_t)NTOK * VOCAB;

    const size_t ND = (size_t)NTOK * D_MODEL;
    float* x             = (float*)d_ws;                         // [N,D] fp32 residual
    __hip_bfloat16* h    = (__hip_bfloat16*)(x + ND);            // [N,D] bf16 LN out
    __hip_bfloat16* qkv  = h + ND;                               // [N,1536] bf16
    __hip_bfloat16* ob   = qkv + 3 * ND;                         // [N,D] bf16
    __hip_bfloat16* hid  = qkv;                                  // [N,4D] bf16 (aliases)
    __hip_bfloat16* wqkvT = ob + ND;                             // [L][1536][512]
    __hip_bfloat16* woT   = wqkvT + (size_t)NLAYER * 1536 * 512; // [L][512][512]
    __hip_bfloat16* w1T   = woT + (size_t)NLAYER * 512 * 512;    // [L][2048][512]
    __hip_bfloat16* w2T   = w1T + (size_t)NLAYER * 2048 * 512;   // [L][512][2048]
    __hip_bfloat16* wuT   = w2T + (size_t)NLAYER * 2048 * 512;   // [128][512]

    // ---- weight convert + transpose ----
    transpose_conv<<<dim3(16, 16, NLAYER), 256, 0, stream>>>(Wq, wqkvT, 512, 512,
        (size_t)512 * 512, (size_t)1536 * 512, 0);
    transpose_conv<<<dim3(16, 16, NLAYER), 256, 0, stream>>>(Wk, wqkvT, 512, 512,
        (size_t)512 * 512, (size_t)1536 * 512, 512);
    transpose_conv<<<dim3(16, 16, NLAYER), 256, 0, stream>>>(Wv, wqkvT, 512, 512,
        (size_t)512 * 512, (size_t)1536 * 512, 1024);
    transpose_conv<<<dim3(16, 16, NLAYER), 256, 0, stream>>>(Wo, woT, 512, 512,
        (size_t)512 * 512, (size_t)512 * 512, 0);
    transpose_conv<<<dim3(64, 16, NLAYER), 256, 0, stream>>>(W1, w1T, 512, 2048,
        (size_t)512 * 2048, (size_t)2048 * 512, 0);
    transpose_conv<<<dim3(16, 64, NLAYER), 256, 0, stream>>>(W2, w2T, 2048, 512,
        (size_t)2048 * 512, (size_t)512 * 2048, 0);
    conv_wu<<<(128 * 512) / 256, 256, 0, stream>>>(Wu, wuT);

    embed_kernel<<<(NTOK * D_MODEL) / 256, 256, 0, stream>>>(input_ids, tok_emb, pos_emb, x);

    for (int l = 0; l < NLAYER; l++) {
        ln_kernel<<<NTOK / 4, 256, 0, stream>>>(x, ln1_g + l * D_MODEL, ln1_b + l * D_MODEL, h);
        mfma_gemm2<0, 0><<<dim3(12, 128), 256, 0, stream>>>(
            h, wqkvT + (size_t)l * 1536 * 512, nullptr, nullptr, qkv, 512, 1536);
        attn_mfma<<<BATCH * NHEAD, 256, 0, stream>>>(qkv, ob);
        mfma_gemm2<0, 1><<<dim3(4, 128), 256, 0, stream>>>(
            ob, woT + (size_t)l * 512 * 512, bo + l * D_MODEL, x, x, 512, 512);
        ln_kernel<<<NTOK / 4, 256, 0, stream>>>(x, ln2_g + l * D_MODEL, ln2_b + l * D_MODEL, h);
        mfma_gemm2<1, 0><<<dim3(16, 128), 256, 0, stream>>>(
            h, w1T + (size_t)l * 2048 * 512, b1 + l * FFDIM, nullptr, hid, 512, 2048);
        mfma_gemm2<0, 1><<<dim3(4, 128), 256, 0, stream>>>(
            hid, w2T + (size_t)l * 2048 * 512, b2 + l * D_MODEL, x, x, 2048, 512);
    }

    ln_kernel<<<NTOK / 4, 256, 0, stream>>>(x, lnf_g, lnf_b, h);
    mfma_gemm<0, 2><<<dim3(1, 128), 256, 0, stream>>>(
        h, wuT, bu, nullptr, out, 512, 128, VOCAB, VOCAB);
    zero_kernel<<<1, 64, 0, stream>>>(loss);
    loss_kernel<<<128, 256, 0, stream>>>(out, targets, loss);
}

// Round 9
// 2184.354 us; speedup vs baseline: 1.2890x; 1.2890x over previous
//
#include <hip/hip_runtime.h>
#include <hip/hip_bf16.h>
#include <math.h>

#define D_MODEL 512
#define NHEAD   8
#define DHEAD   64
#define SEQ     64
#define BATCH   256
#define NLAYER  8
#define VOCAB   66
#define FFDIM   2048
#define NTOK    (BATCH * SEQ)   // 16384 rows

typedef __attribute__((ext_vector_type(8))) short short8;    // 8 bf16 = 4 VGPRs
typedef __attribute__((ext_vector_type(4))) float f32x4;
typedef __attribute__((ext_vector_type(16))) float f32x16;

__device__ inline void async_copy16(const void* g, void* l) {
    __builtin_amdgcn_global_load_lds(
        (const __attribute__((address_space(1))) void*)g,
        (__attribute__((address_space(3))) void*)l,
        16, 0, 0);
}

// ---------------- weight fp32 [K,M] -> bf16 [M,K] transpose ----------------
__global__ __launch_bounds__(256) void transpose_conv(
        const float* __restrict__ W, __hip_bfloat16* __restrict__ Wt,
        int K, int M, size_t inLS, size_t outLS, int rowOff) {
    __shared__ float tile[32][33];
    int m0 = blockIdx.x * 32, k0 = blockIdx.y * 32;
    const float* Wl = W + blockIdx.z * inLS;
    __hip_bfloat16* Wtl = Wt + blockIdx.z * outLS;
    int t = threadIdx.x;
    #pragma unroll
    for (int p = 0; p < 4; p++) {
        int idx = t + p * 256;
        int kr = idx >> 5, mc = idx & 31;
        tile[kr][mc] = Wl[(size_t)(k0 + kr) * M + m0 + mc];
    }
    __syncthreads();
    #pragma unroll
    for (int p = 0; p < 4; p++) {
        int idx = t + p * 256;
        int mr = idx >> 5, kc = idx & 31;
        Wtl[(size_t)(rowOff + m0 + mr) * K + k0 + kc] = __float2bfloat16(tile[kc][mr]);
    }
}

// ---------------- Wu fp32 [512,66] -> bf16 [128,512] transposed, zero-padded ----
__global__ __launch_bounds__(256) void conv_wu(
        const float* __restrict__ Wu, __hip_bfloat16* __restrict__ WuT) {
    int idx = blockIdx.x * 256 + threadIdx.x;   // over 128*512
    int m = idx >> 9, k = idx & 511;
    WuT[idx] = __float2bfloat16(m < VOCAB ? Wu[(size_t)k * VOCAB + m] : 0.f);
}

// ---------------- embedding (fp32 residual) ----------------
__global__ void embed_kernel(const int* __restrict__ ids, const float* __restrict__ tok,
                             const float* __restrict__ pos, float* __restrict__ x) {
    int idx = blockIdx.x * 256 + threadIdx.x;
    int n = idx >> 9;
    int d = idx & 511;
    int s = n & (SEQ - 1);
    x[idx] = tok[ids[n] * D_MODEL + d] + pos[s * D_MODEL + d];
}

// ---------------- layernorm: wave per row, no barriers ----------------
__global__ __launch_bounds__(256) void ln_kernel(
        const float* __restrict__ x, const float* __restrict__ g,
        const float* __restrict__ b, __hip_bfloat16* __restrict__ y) {
    int row = blockIdx.x * 4 + (threadIdx.x >> 6);
    int lane = threadIdx.x & 63;
    const float* xr = x + (size_t)row * D_MODEL + lane * 8;
    f32x4 v0 = *(const f32x4*)xr;
    f32x4 v1 = *(const f32x4*)(xr + 4);
    float s = 0.f, ss = 0.f;
    #pragma unroll
    for (int e = 0; e < 4; e++) { s += v0[e] + v1[e]; ss += v0[e] * v0[e] + v1[e] * v1[e]; }
    #pragma unroll
    for (int o = 1; o < 64; o <<= 1) {
        s  += __shfl_xor(s, o);
        ss += __shfl_xor(ss, o);
    }
    float mean = s / (float)D_MODEL;
    float var = (ss - (float)D_MODEL * mean * mean) / (float)(D_MODEL - 1);
    float denom = sqrtf(fmaxf(var, 0.f)) + 1e-10f;
    f32x4 g0 = *(const f32x4*)(g + lane * 8);
    f32x4 g1 = *(const f32x4*)(g + lane * 8 + 4);
    f32x4 b0 = *(const f32x4*)(b + lane * 8);
    f32x4 b1 = *(const f32x4*)(b + lane * 8 + 4);
    short8 outv;
    #pragma unroll
    for (int e = 0; e < 4; e++) {
        outv[e]     = ((__hip_bfloat16_raw)__float2bfloat16((v0[e] - mean) / denom * g0[e] + b0[e])).x;
        outv[e + 4] = ((__hip_bfloat16_raw)__float2bfloat16((v1[e] - mean) / denom * g1[e] + b1[e])).x;
    }
    *(short8*)((short*)y + (size_t)row * D_MODEL + lane * 8) = outv;
}

// ---------------- bf16 MFMA GEMM (32x32x16, BK=64, XOR-swizzled LDS) ----------------
// A [N,K] bf16 row-major; Bt [M,K] bf16 row-major (pre-transposed weight).
// 128x128 tile, 4 waves 2x2 of 64x64. Fragments loaded PER-kk (4 live short8 =
// 16 VGPRs) + __launch_bounds__(256,4) caps regs at 128/wave (64 AGPR acc +
// <=64 VGPR) -> 4 waves/SIMD instead of 2. // R6/R7/R8 taught: occupancy,
// not inner-loop width, is the binding constraint in this short-K regime.
// OUTMODE 0: bf16 store. 1: fp32 store + addsrc residual.
// 2: fp32 store, ldc row stride, col < mstore guard (logits).
template <int ACT, int OUTMODE>
__global__ __launch_bounds__(256, 4) void mfma_gemm(
        const __hip_bfloat16* __restrict__ A, const __hip_bfloat16* __restrict__ Bt,
        const float* __restrict__ bias, const float* addsrc,
        void* Cout, int K, int M, int ldc, int mstore) {
    __shared__ __align__(16) short As[128 * 64];   // 16 KB
    __shared__ __align__(16) short Bs[128 * 64];   // 16 KB
    int tid = threadIdx.x;
    int lane = tid & 63, wave = tid >> 6;
    int row0 = blockIdx.y * 128, col0 = blockIdx.x * 128;
    int wr = (wave >> 1) * 64, wc = (wave & 1) * 64;
    int l31 = lane & 31, h32 = lane >> 5;
    int l7 = l31 & 7;

    f32x16 acc[2][2] = {};

    int srow[4], skg[4];
    #pragma unroll
    for (int s = 0; s < 4; s++) {
        int u = s * 256 + tid;
        srow[s] = u >> 3;
        skg[s] = (u & 7) ^ (srow[s] & 7);
    }

    for (int k0 = 0; k0 < K; k0 += 64) {
        #pragma unroll
        for (int s = 0; s < 4; s++) {
            int u = s * 256 + tid;
            async_copy16((const short*)A + (size_t)(row0 + srow[s]) * K + k0 + skg[s] * 8,
                         As + u * 8);
            async_copy16((const short*)Bt + (size_t)(col0 + srow[s]) * K + k0 + skg[s] * 8,
                         Bs + u * 8);
        }
        __syncthreads();
        #pragma unroll
        for (int kk = 0; kk < 4; kk++) {
            int kg = kk * 2 + h32;
            int c = kg ^ l7;
            short8 af0 = *(const short8*)(As + ((wr + l31) * 8 + c) * 8);
            short8 af1 = *(const short8*)(As + ((wr + 32 + l31) * 8 + c) * 8);
            short8 bf0 = *(const short8*)(Bs + ((wc + l31) * 8 + c) * 8);
            short8 bf1 = *(const short8*)(Bs + ((wc + 32 + l31) * 8 + c) * 8);
            acc[0][0] = __builtin_amdgcn_mfma_f32_32x32x16_bf16(af0, bf0, acc[0][0], 0, 0, 0);
            acc[0][1] = __builtin_amdgcn_mfma_f32_32x32x16_bf16(af0, bf1, acc[0][1], 0, 0, 0);
            acc[1][0] = __builtin_amdgcn_mfma_f32_32x32x16_bf16(af1, bf0, acc[1][0], 0, 0, 0);
            acc[1][1] = __builtin_amdgcn_mfma_f32_32x32x16_bf16(af1, bf1, acc[1][1], 0, 0, 0);
        }
        __syncthreads();
    }

    // C/D layout: col = lane&31, row = (reg&3) + 8*(reg>>2) + 4*(lane>>5)
    #pragma unroll
    for (int j = 0; j < 2; j++) {
        int col = col0 + wc + j * 32 + l31;
        if (OUTMODE == 2 && col >= mstore) continue;
        float bv = bias ? bias[col] : 0.f;
        #pragma unroll
        for (int i = 0; i < 2; i++) {
            int rbase = row0 + wr + i * 32 + 4 * h32;
            #pragma unroll
            for (int r = 0; r < 16; r++) {
                int row = rbase + (r & 3) + 8 * (r >> 2);
                float v = acc[i][j][r] + bv;
                if (OUTMODE == 1) v += addsrc[(size_t)row * M + col];
                if (ACT == 1) v = 0.5f * v * (1.f + erff(v * 0.70710678118654752f));
                if (OUTMODE == 0)
                    ((__hip_bfloat16*)Cout)[(size_t)row * M + col] = __float2bfloat16(v);
                else
                    ((float*)Cout)[(size_t)row * ldc + col] = v;
            }
        }
    }
}

// ---------------- MFMA causal attention: one block per (b,h) ----------------
#define PSTRIDE 72
__global__ __launch_bounds__(256) void attn_mfma(
        const __hip_bfloat16* __restrict__ QKV, __hip_bfloat16* __restrict__ O) {
    __shared__ __align__(16) short Vt[64 * PSTRIDE];   // Vt[c][j] = V[j][c]
    __shared__ __align__(16) short P[64 * PSTRIDE];    // P[r][j]
    int bh = blockIdx.x;
    int b = bh >> 3, h = bh & 7;
    int t = threadIdx.x;
    int lane = t & 63, wave = t >> 6;
    int l15 = lane & 15, quad = lane >> 4;
    const float scale = 0.04419417382415922f;  // 1/sqrt(512)
    const short* base = (const short*)QKV + (size_t)(b * SEQ) * 1536 + h * DHEAD;

    // cooperative V transpose into LDS
    {
        int j0 = (t >> 3) * 2;
        int c0 = (t & 7) * 8;
        const short* vrow = base + 1024 + (size_t)j0 * 1536 + c0;
        short8 va = *(const short8*)vrow;
        short8 vb = *(const short8*)(vrow + 1536);
        #pragma unroll
        for (int s = 0; s < 8; s++) {
            unsigned int packed = ((unsigned int)(unsigned short)vb[s] << 16) |
                                  (unsigned int)(unsigned short)va[s];
            *(unsigned int*)&Vt[(c0 + s) * PSTRIDE + j0] = packed;
        }
    }

    // QK^T for this wave's 16 rows
    int r0 = wave * 16;
    short8 aq[2], bk[4][2];
    #pragma unroll
    for (int k = 0; k < 2; k++)
        aq[k] = *(const short8*)(base + (size_t)(r0 + l15) * 1536 + quad * 8 + 32 * k);
    #pragma unroll
    for (int j = 0; j < 4; j++)
        #pragma unroll
        for (int k = 0; k < 2; k++)
            bk[j][k] = *(const short8*)(base + 512 + (size_t)(j * 16 + l15) * 1536 + quad * 8 + 32 * k);

    f32x4 sc[4];
    #pragma unroll
    for (int j = 0; j < 4; j++) {
        f32x4 z = {};
        z = __builtin_amdgcn_mfma_f32_16x16x32_bf16(aq[0], bk[j][0], z, 0, 0, 0);
        sc[j] = __builtin_amdgcn_mfma_f32_16x16x32_bf16(aq[1], bk[j][1], z, 0, 0, 0);
    }

    // softmax per row
    float p[4][4];
    #pragma unroll
    for (int reg = 0; reg < 4; reg++) {
        int r = r0 + quad * 4 + reg;
        float m = -INFINITY;
        #pragma unroll
        for (int j = 0; j < 4; j++) {
            int c = j * 16 + l15;
            float s = (c <= r) ? sc[j][reg] * scale : -INFINITY;
            p[j][reg] = s;
            m = fmaxf(m, s);
        }
        #pragma unroll
        for (int o = 1; o < 16; o <<= 1) m = fmaxf(m, __shfl_xor(m, o));
        float sum = 0.f;
        #pragma unroll
        for (int j = 0; j < 4; j++) {
            float e = (p[j][reg] == -INFINITY) ? 0.f : expf(p[j][reg] - m);
            p[j][reg] = e;
            sum += e;
        }
        #pragma unroll
        for (int o = 1; o < 16; o <<= 1) sum += __shfl_xor(sum, o);
        float inv = 1.f / sum;
        #pragma unroll
        for (int j = 0; j < 4; j++) p[j][reg] *= inv;
    }

    // write P (bf16) to LDS
    #pragma unroll
    for (int j = 0; j < 4; j++)
        #pragma unroll
        for (int reg = 0; reg < 4; reg++) {
            int r = r0 + quad * 4 + reg;
            P[r * PSTRIDE + j * 16 + l15] =
                ((__hip_bfloat16_raw)__float2bfloat16(p[j][reg])).x;
        }

    __syncthreads();

    // PV
    short8 ap[2];
    #pragma unroll
    for (int k = 0; k < 2; k++)
        ap[k] = *(const short8*)(P + (r0 + l15) * PSTRIDE + quad * 8 + 32 * k);
    #pragma unroll
    for (int jt = 0; jt < 4; jt++) {
        short8 bv0 = *(const short8*)(Vt + (jt * 16 + l15) * PSTRIDE + quad * 8);
        short8 bv1 = *(const short8*)(Vt + (jt * 16 + l15) * PSTRIDE + quad * 8 + 32);
        f32x4 o = {};
        o = __builtin_amdgcn_mfma_f32_16x16x32_bf16(ap[0], bv0, o, 0, 0, 0);
        o = __builtin_amdgcn_mfma_f32_16x16x32_bf16(ap[1], bv1, o, 0, 0, 0);
        #pragma unroll
        for (int reg = 0; reg < 4; reg++) {
            int r = r0 + quad * 4 + reg;
            int c = jt * 16 + l15;
            O[(size_t)(b * SEQ + r) * D_MODEL + h * DHEAD + c] = __float2bfloat16(o[reg]);
        }
    }
}

// ---------------- loss: grid-stride waves, one atomic per wave ----------------
__global__ void zero_kernel(float* p) { if (threadIdx.x == 0) *p = 0.f; }

__global__ __launch_bounds__(256) void loss_kernel(
        const float* __restrict__ lg, const int* __restrict__ tgt,
        float* __restrict__ loss) {
    int wave = threadIdx.x >> 6;
    int l = threadIdx.x & 63;
    float local = 0.f;
    for (int row = blockIdx.x * 4 + wave; row < NTOK; row += gridDim.x * 4) {
        const float* lr = lg + (size_t)row * VOCAB;
        float a = lr[l];
        float bx = (l < VOCAB - 64) ? lr[64 + l] : -INFINITY;
        float m = fmaxf(a, bx);
        #pragma unroll
        for (int o = 32; o >= 1; o >>= 1) m = fmaxf(m, __shfl_xor(m, o));
        float s = expf(a - m) + ((l < VOCAB - 64) ? expf(bx - m) : 0.f);
        #pragma unroll
        for (int o = 32; o >= 1; o >>= 1) s += __shfl_xor(s, o);
        if (l == 0) local += lr[tgt[row]] - m - logf(s);
    }
    if (l == 0) atomicAdd(loss, -local / (float)NTOK);
}

extern "C" void kernel_launch(void* const* d_in, const int* in_sizes, int n_in,
                              void* d_out, int out_size, void* d_ws, size_t ws_size,
                              hipStream_t stream) {
    const int*   input_ids = (const int*)  d_in[0];
    const int*   targets   = (const int*)  d_in[1];
    const float* tok_emb   = (const float*)d_in[2];
    const float* pos_emb   = (const float*)d_in[3];
    const float* Wq        = (const float*)d_in[4];
    const float* Wk        = (const float*)d_in[5];
    const float* Wv        = (const float*)d_in[6];
    const float* Wo        = (const float*)d_in[7];
    const float* bo        = (const float*)d_in[8];
    const float* W1        = (const float*)d_in[9];
    const float* b1        = (const float*)d_in[10];
    const float* W2        = (const float*)d_in[11];
    const float* b2        = (const float*)d_in[12];
    const float* ln1_g     = (const float*)d_in[13];
    const float* ln1_b     = (const float*)d_in[14];
    const float* ln2_g     = (const float*)d_in[15];
    const float* ln2_b     = (const float*)d_in[16];
    const float* lnf_g     = (const float*)d_in[17];
    const float* lnf_b     = (const float*)d_in[18];
    const float* Wu        = (const float*)d_in[19];
    const float* bu        = (const float*)d_in[20];

    float* out  = (float*)d_out;
    float* loss = out + (size_t)NTOK * VOCAB;

    const size_t ND = (size_t)NTOK * D_MODEL;
    float* x             = (float*)d_ws;                         // [N,D] fp32 residual
    __hip_bfloat16* h    = (__hip_bfloat16*)(x + ND);            // [N,D] bf16 LN out
    __hip_bfloat16* qkv  = h + ND;                               // [N,1536] bf16
    __hip_bfloat16* ob   = qkv + 3 * ND;                         // [N,D] bf16
    __hip_bfloat16* hid  = qkv;                                  // [N,4D] bf16 (aliases)
    __hip_bfloat16* wqkvT = ob + ND;                             // [L][1536][512]
    __hip_bfloat16* woT   = wqkvT + (size_t)NLAYER * 1536 * 512; // [L][512][512]
    __hip_bfloat16* w1T   = woT + (size_t)NLAYER * 512 * 512;    // [L][2048][512]
    __hip_bfloat16* w2T   = w1T + (size_t)NLAYER * 2048 * 512;   // [L][512][2048]
    __hip_bfloat16* wuT   = w2T + (size_t)NLAYER * 2048 * 512;   // [128][512]

    // ---- weight convert + transpose ----
    transpose_conv<<<dim3(16, 16, NLAYER), 256, 0, stream>>>(Wq, wqkvT, 512, 512,
        (size_t)512 * 512, (size_t)1536 * 512, 0);
    transpose_conv<<<dim3(16, 16, NLAYER), 256, 0, stream>>>(Wk, wqkvT, 512, 512,
        (size_t)512 * 512, (size_t)1536 * 512, 512);
    transpose_conv<<<dim3(16, 16, NLAYER), 256, 0, stream>>>(Wv, wqkvT, 512, 512,
        (size_t)512 * 512, (size_t)1536 * 512, 1024);
    transpose_conv<<<dim3(16, 16, NLAYER), 256, 0, stream>>>(Wo, woT, 512, 512,
        (size_t)512 * 512, (size_t)512 * 512, 0);
    transpose_conv<<<dim3(64, 16, NLAYER), 256, 0, stream>>>(W1, w1T, 512, 2048,
        (size_t)512 * 2048, (size_t)2048 * 512, 0);
    transpose_conv<<<dim3(16, 64, NLAYER), 256, 0, stream>>>(W2, w2T, 2048, 512,
        (size_t)2048 * 512, (size_t)512 * 2048, 0);
    conv_wu<<<(128 * 512) / 256, 256, 0, stream>>>(Wu, wuT);

    embed_kernel<<<(NTOK * D_MODEL) / 256, 256, 0, stream>>>(input_ids, tok_emb, pos_emb, x);

    for (int l = 0; l < NLAYER; l++) {
        ln_kernel<<<NTOK / 4, 256, 0, stream>>>(x, ln1_g + l * D_MODEL, ln1_b + l * D_MODEL, h);
        mfma_gemm<0, 0><<<dim3(12, 128), 256, 0, stream>>>(
            h, wqkvT + (size_t)l * 1536 * 512, nullptr, nullptr, qkv, 512, 1536, 1536, 1536);
        attn_mfma<<<BATCH * NHEAD, 256, 0, stream>>>(qkv, ob);
        mfma_gemm<0, 1><<<dim3(4, 128), 256, 0, stream>>>(
            ob, woT + (size_t)l * 512 * 512, bo + l * D_MODEL, x, x, 512, 512, 512, 512);
        ln_kernel<<<NTOK / 4, 256, 0, stream>>>(x, ln2_g + l * D_MODEL, ln2_b + l * D_MODEL, h);
        mfma_gemm<1, 0><<<dim3(16, 128), 256, 0, stream>>>(
            h, w1T + (size_t)l * 2048 * 512, b1 + l * FFDIM, nullptr, hid, 512, 2048, 2048, 2048);
        mfma_gemm<0, 1><<<dim3(4, 128), 256, 0, stream>>>(
            hid, w2T + (size_t)l * 2048 * 512, b2 + l * D_MODEL, x, x, 2048, 512, 512, 512);
    }

    ln_kernel<<<NTOK / 4, 256, 0, stream>>>(x, lnf_g, lnf_b, h);
    mfma_gemm<0, 2><<<dim3(1, 128), 256, 0, stream>>>(
        h, wuT, bu, nullptr, out, 512, 128, VOCAB, VOCAB);
    zero_kernel<<<1, 64, 0, stream>>>(loss);
    loss_kernel<<<128, 256, 0, stream>>>(out, targets, loss);
}